// Round 1
// baseline (317.484 us; speedup 1.0000x reference)
//
#include <hip/hip_runtime.h>
#include <hip/hip_bf16.h>

#define BATCH 1024
#define SEQ 256
#define HIDDEN 128
#define VOCAB 60

// Precompute embW[v][i] = sum_j emb[v][j] * W_ih[i][j]   (= (emb @ W_ih^T)[v][i])
// Grid: VOCAB blocks x HIDDEN threads. Tiny (~1 MFLOP).
__global__ void rnn_prep_embw(const float* __restrict__ emb,
                              const float* __restrict__ W_ih,
                              float* __restrict__ embW) {
    const int v = blockIdx.x;
    const int i = threadIdx.x;
    __shared__ __align__(16) float e[HIDDEN];
    e[i] = emb[v * HIDDEN + i];
    __syncthreads();
    const float4* wrow = (const float4*)(W_ih + i * HIDDEN);
    const float4* e4 = (const float4*)e;
    float a0 = 0.f, a1 = 0.f, a2 = 0.f, a3 = 0.f;
#pragma unroll
    for (int j = 0; j < HIDDEN / 4; ++j) {
        float4 w = wrow[j];
        float4 h = e4[j];
        a0 += w.x * h.x;
        a1 += w.y * h.y;
        a2 += w.z * h.z;
        a3 += w.w * h.w;
    }
    embW[v * HIDDEN + i] = (a0 + a1) + (a2 + a3);
}

// One block per batch element, 128 threads. Thread i keeps W_hh row i in VGPRs.
// h double-buffered in LDS; one barrier per step; embW lookup prefetched one
// step ahead. Runs only lengths[b] steps; fuses the final FC epilogue.
__global__ void __launch_bounds__(HIDDEN, 2)
rnn_main(const int* __restrict__ x,
         const int* __restrict__ lengths,
         const float* __restrict__ embW,
         const float* __restrict__ W_hh,
         const float* __restrict__ W_fc,
         const float* __restrict__ b_fc,
         float* __restrict__ out) {
    const int b = blockIdx.x;
    const int i = threadIdx.x;

    __shared__ __align__(16) float hbuf[2][HIDDEN];
    __shared__ int xrow[SEQ];

    // Stage this batch element's token row (coalesced, 2 ints/thread).
    xrow[i] = x[b * SEQ + i];
    xrow[i + HIDDEN] = x[b * SEQ + HIDDEN + i];

    // W_hh row i -> 128 VGPRs (32 x float4). ~64 KB table, L2/L3 resident
    // after the first wave touches it.
    float w[HIDDEN];
    {
        const float4* wrow = (const float4*)(W_hh + i * HIDDEN);
#pragma unroll
        for (int j = 0; j < HIDDEN / 4; ++j) {
            float4 v = wrow[j];
            w[4 * j + 0] = v.x;
            w[4 * j + 1] = v.y;
            w[4 * j + 2] = v.z;
            w[4 * j + 3] = v.w;
        }
    }

    const int len = lengths[b];  // in [1, SEQ]
    hbuf[0][i] = 0.0f;
    __syncthreads();

    // Prefetch embW for t=0.
    float pre = embW[xrow[0] * HIDDEN + i];

    int cur = 0;
    for (int t = 0; t < len; ++t) {
        float acc = pre;
        // Branch-free prefetch of next step's input projection (clamped).
        const int tn = (t + 1 < len) ? (t + 1) : t;
        pre = embW[xrow[tn] * HIDDEN + i];

        // h_new[i] = tanh(acc + dot(W_hh[i,:], h)) ; h broadcast from LDS.
        const float4* h4 = (const float4*)hbuf[cur];
        float a0 = 0.f, a1 = 0.f, a2 = 0.f, a3 = 0.f;
#pragma unroll
        for (int j = 0; j < HIDDEN / 4; ++j) {
            float4 hv = h4[j];
            a0 += w[4 * j + 0] * hv.x;
            a1 += w[4 * j + 1] * hv.y;
            a2 += w[4 * j + 2] * hv.z;
            a3 += w[4 * j + 3] * hv.w;
        }
        acc += (a0 + a1) + (a2 + a3);

        const float hn = tanhf(acc);
        hbuf[cur ^ 1][i] = hn;
        __syncthreads();
        cur ^= 1;
    }

    // Final h lives in hbuf[cur]. Epilogue: out[b][v] = h . W_fc[v,:] + b_fc[v].
    if (i < VOCAB) {
        const float4* h4 = (const float4*)hbuf[cur];
        const float4* wf = (const float4*)(W_fc + i * HIDDEN);
        float a0 = 0.f, a1 = 0.f, a2 = 0.f, a3 = 0.f;
#pragma unroll
        for (int j = 0; j < HIDDEN / 4; ++j) {
            float4 wv = wf[j];
            float4 hv = h4[j];
            a0 += wv.x * hv.x;
            a1 += wv.y * hv.y;
            a2 += wv.z * hv.z;
            a3 += wv.w * hv.w;
        }
        out[b * VOCAB + i] = (a0 + a1) + (a2 + a3) + b_fc[i];
    }
}

extern "C" void kernel_launch(void* const* d_in, const int* in_sizes, int n_in,
                              void* d_out, int out_size, void* d_ws, size_t ws_size,
                              hipStream_t stream) {
    const int* x = (const int*)d_in[0];          // [B, T] int32
    const int* lengths = (const int*)d_in[1];    // [B] int32
    const float* emb = (const float*)d_in[2];    // [V, H]
    const float* W_ih = (const float*)d_in[3];   // [H, H]
    const float* W_hh = (const float*)d_in[4];   // [H, H]
    const float* W_fc = (const float*)d_in[5];   // [V, H]
    const float* b_fc = (const float*)d_in[6];   // [V]
    float* out = (float*)d_out;                  // [B, V]

    float* embW = (float*)d_ws;                  // VOCAB*HIDDEN floats (30 KB)

    rnn_prep_embw<<<VOCAB, HIDDEN, 0, stream>>>(emb, W_ih, embW);
    rnn_main<<<BATCH, HIDDEN, 0, stream>>>(x, lengths, embW, W_hh, W_fc, b_fc, out);
}

// Round 2
// 260.917 us; speedup vs baseline: 1.2168x; 1.2168x over previous
//
#include <hip/hip_runtime.h>
#include <hip/hip_bf16.h>

#define BATCH 1024
#define SEQ 256
#define HIDDEN 128
#define VOCAB 60
#define MTILE 16
#define ASTRIDE 136   // bf16 elems per A row: 128 + 8 pad (keeps 16B align, rotates banks)

typedef __bf16 bf16x8 __attribute__((ext_vector_type(8)));
typedef float f32x4 __attribute__((ext_vector_type(4)));

__device__ __forceinline__ float fast_tanh(float x) {
    // tanh(x) = 1 - 2/(exp(2x)+1); exp(2x) = exp2(x * 2*log2e). Branch-free,
    // exact +-1 saturation (exp2->inf -> rcp->0; exp2->0 -> 1-2 = -1).
    float e = __builtin_amdgcn_exp2f(x * 2.8853900817779268f);
    return __builtin_fmaf(-2.0f, __builtin_amdgcn_rcpf(e + 1.0f), 1.0f);
}

// embW[v][i] = sum_j emb[v][j] * W_ih[i][j]  (fp32, exact input projection table)
__global__ void rnn_prep_embw(const float* __restrict__ emb,
                              const float* __restrict__ W_ih,
                              float* __restrict__ embW) {
    const int v = blockIdx.x;
    const int i = threadIdx.x;
    __shared__ __align__(16) float e[HIDDEN];
    e[i] = emb[v * HIDDEN + i];
    __syncthreads();
    const float4* wrow = (const float4*)(W_ih + i * HIDDEN);
    const float4* e4 = (const float4*)e;
    float a0 = 0.f, a1 = 0.f, a2 = 0.f, a3 = 0.f;
#pragma unroll
    for (int j = 0; j < HIDDEN / 4; ++j) {
        float4 w = wrow[j];
        float4 h = e4[j];
        a0 += w.x * h.x; a1 += w.y * h.y; a2 += w.z * h.z; a3 += w.w * h.w;
    }
    embW[v * HIDDEN + i] = (a0 + a1) + (a2 + a3);
}

// One block per 16 batch rows. 4 waves; wave w owns output cols [32w, 32w+32)
// = two 16x16 N-tiles. W_hh lives in VGPRs as hi/lo bf16 B-fragments.
// h lives in LDS as hi/lo bf16 A-tiles (double buffered). Recurrent step:
//   C = embW_gather (fp32 seed); C += A_hi*B_hi + A_lo*B_hi + A_hi*B_lo
//   h = fast_tanh(C); capture h at t+1==len[r]; write hi/lo back to A[next].
__global__ void __launch_bounds__(256)
rnn_mfma(const int* __restrict__ x, const int* __restrict__ lengths,
         const float* __restrict__ embW, const float* __restrict__ W_hh,
         const float* __restrict__ W_fc, const float* __restrict__ b_fc,
         float* __restrict__ out) {
    const int tid = threadIdx.x;
    const int wave = tid >> 6;
    const int lane = tid & 63;
    const int q = lane >> 4;     // 0..3  (k-group / row-group)
    const int r16 = lane & 15;   // 0..15 (A row / B,N col)
    const int c0 = wave * 32;
    const int b0 = blockIdx.x * MTILE;

    __shared__ __align__(16) __bf16 Ahi[2][MTILE][ASTRIDE];
    __shared__ __align__(16) __bf16 Alo[2][MTILE][ASTRIDE];
    __shared__ int xs[MTILE][SEQ];
    __shared__ __align__(16) float hfin[MTILE][HIDDEN];
    __shared__ int lenbuf[MTILE];

    // Stage tokens (coalesced) and lengths.
    for (int idx = tid; idx < MTILE * SEQ; idx += 256) {
        int r = idx >> 8, t = idx & (SEQ - 1);
        xs[r][t] = x[(b0 + r) * SEQ + t];
    }
    if (tid < MTILE) lenbuf[tid] = lengths[b0 + tid];

    // Zero h (h_0 = 0) in both A buffers.
    {
        __bf16 z = (__bf16)0.0f;
        for (int idx = tid; idx < 2 * MTILE * ASTRIDE; idx += 256) {
            ((__bf16*)Ahi)[idx] = z;
            ((__bf16*)Alo)[idx] = z;
        }
    }

    // B-fragments: B[k][n] with n = lane&15, k = kc*32 + q*8 + j.
    // B[k][n] = W_hh[n_global][k]  (z = h @ W_hh^T).
    bf16x8 Bhi[2][4], Blo[2][4];
#pragma unroll
    for (int n = 0; n < 2; ++n) {
        const float* wrow = W_hh + (c0 + 16 * n + r16) * HIDDEN + q * 8;
#pragma unroll
        for (int kc = 0; kc < 4; ++kc) {
            const float* p = wrow + kc * 32;
#pragma unroll
            for (int j = 0; j < 8; ++j) {
                float f = p[j];
                __bf16 h = (__bf16)f;
                Bhi[n][kc][j] = h;
                Blo[n][kc][j] = (__bf16)(f - (float)h);
            }
        }
    }

    __syncthreads();

    int len4[4];
#pragma unroll
    for (int v = 0; v < 4; ++v) len4[v] = lenbuf[4 * q + v];
    int lenmax = 0;
    for (int r = 0; r < MTILE; ++r) lenmax = max(lenmax, lenbuf[r]);

    // fp32 embW seed for t=0 (C layout: lane holds rows 4q+v, cols c0+r16 / +16).
    f32x4 pre0, pre1;
#pragma unroll
    for (int v = 0; v < 4; ++v) {
        int tok = xs[4 * q + v][0];
        pre0[v] = embW[tok * HIDDEN + c0 + r16];
        pre1[v] = embW[tok * HIDDEN + c0 + 16 + r16];
    }

    int cur = 0;
    f32x4 hout0 = {0.f, 0.f, 0.f, 0.f}, hout1 = {0.f, 0.f, 0.f, 0.f};

    for (int t = 0; t < lenmax; ++t) {
        f32x4 acc0 = pre0, acc1 = pre1;             // seeded with embW (fp32 exact)
        f32x4 d0 = {0.f, 0.f, 0.f, 0.f}, d1 = {0.f, 0.f, 0.f, 0.f};
#pragma unroll
        for (int kc = 0; kc < 4; ++kc) {
            bf16x8 ah = *(const bf16x8*)&Ahi[cur][r16][kc * 32 + q * 8];
            bf16x8 al = *(const bf16x8*)&Alo[cur][r16][kc * 32 + q * 8];
            acc0 = __builtin_amdgcn_mfma_f32_16x16x32_bf16(ah, Bhi[0][kc], acc0, 0, 0, 0);
            acc1 = __builtin_amdgcn_mfma_f32_16x16x32_bf16(ah, Bhi[1][kc], acc1, 0, 0, 0);
            d0   = __builtin_amdgcn_mfma_f32_16x16x32_bf16(al, Bhi[0][kc], d0, 0, 0, 0);
            d0   = __builtin_amdgcn_mfma_f32_16x16x32_bf16(ah, Blo[0][kc], d0, 0, 0, 0);
            d1   = __builtin_amdgcn_mfma_f32_16x16x32_bf16(al, Bhi[1][kc], d1, 0, 0, 0);
            d1   = __builtin_amdgcn_mfma_f32_16x16x32_bf16(ah, Blo[1][kc], d1, 0, 0, 0);
        }

        // Prefetch next step's embW contribution (hidden under this step's tail).
        int tn = (t + 1 < lenmax) ? t + 1 : t;
        f32x4 pn0, pn1;
#pragma unroll
        for (int v = 0; v < 4; ++v) {
            int tok = xs[4 * q + v][tn];
            pn0[v] = embW[tok * HIDDEN + c0 + r16];
            pn1[v] = embW[tok * HIDDEN + c0 + 16 + r16];
        }

        const int nxt = cur ^ 1;
#pragma unroll
        for (int v = 0; v < 4; ++v) {
            float h0 = fast_tanh(acc0[v] + d0[v]);
            float h1 = fast_tanh(acc1[v] + d1[v]);
            if (t + 1 == len4[v]) { hout0[v] = h0; hout1[v] = h1; }
            int rr = 4 * q + v;
            __bf16 g0 = (__bf16)h0;
            Ahi[nxt][rr][c0 + r16] = g0;
            Alo[nxt][rr][c0 + r16] = (__bf16)(h0 - (float)g0);
            __bf16 g1 = (__bf16)h1;
            Ahi[nxt][rr][c0 + 16 + r16] = g1;
            Alo[nxt][rr][c0 + 16 + r16] = (__bf16)(h1 - (float)g1);
        }
        __syncthreads();
        cur = nxt;
        pre0 = pn0; pre1 = pn1;
    }

    // Gather captured h (fp32) and run the tiny FC epilogue.
#pragma unroll
    for (int v = 0; v < 4; ++v) {
        hfin[4 * q + v][c0 + r16] = hout0[v];
        hfin[4 * q + v][c0 + 16 + r16] = hout1[v];
    }
    __syncthreads();

    const int r = tid >> 4;       // 0..15
    const int vbase = tid & 15;   // 0..15
    const float4* hv = (const float4*)hfin[r];
    for (int vo = vbase; vo < VOCAB; vo += 16) {
        const float4* wf = (const float4*)(W_fc + vo * HIDDEN);
        float a0 = 0.f, a1 = 0.f, a2 = 0.f, a3 = 0.f;
#pragma unroll
        for (int j = 0; j < HIDDEN / 4; ++j) {
            float4 a = hv[j];
            float4 w = wf[j];
            a0 += a.x * w.x; a1 += a.y * w.y; a2 += a.z * w.z; a3 += a.w * w.w;
        }
        out[(b0 + r) * VOCAB + vo] = (a0 + a1) + (a2 + a3) + b_fc[vo];
    }
}

extern "C" void kernel_launch(void* const* d_in, const int* in_sizes, int n_in,
                              void* d_out, int out_size, void* d_ws, size_t ws_size,
                              hipStream_t stream) {
    const int* x = (const int*)d_in[0];          // [B, T] int32
    const int* lengths = (const int*)d_in[1];    // [B] int32
    const float* emb = (const float*)d_in[2];    // [V, H]
    const float* W_ih = (const float*)d_in[3];   // [H, H]
    const float* W_hh = (const float*)d_in[4];   // [H, H]
    const float* W_fc = (const float*)d_in[5];   // [V, H]
    const float* b_fc = (const float*)d_in[6];   // [V]
    float* out = (float*)d_out;                  // [B, V]

    float* embW = (float*)d_ws;                  // VOCAB*HIDDEN floats (30 KB)

    rnn_prep_embw<<<VOCAB, HIDDEN, 0, stream>>>(emb, W_ih, embW);
    rnn_mfma<<<BATCH / MTILE, 256, 0, stream>>>(x, lengths, embW, W_hh, W_fc, b_fc, out);
}

// Round 3
// 210.623 us; speedup vs baseline: 1.5074x; 1.2388x over previous
//
#include <hip/hip_runtime.h>
#include <hip/hip_bf16.h>

#define BATCH 1024
#define SEQ 256
#define HIDDEN 128
#define VOCAB 60
#define MTILE 16
#define ASTRIDE 136   // fp16 elems per A row: 128 + 8 pad (68 dwords == 4 mod 32 -> uniform b128 banks)
#define XSTRIDE (SEQ + 1)  // pad token rows off bank 0

typedef _Float16 f16x8 __attribute__((ext_vector_type(8)));
typedef float f32x4 __attribute__((ext_vector_type(4)));

__device__ __forceinline__ float fast_tanh(float x) {
    // tanh(x) = 1 - 2/(exp(2x)+1); exp(2x)=exp2(x*2*log2e). Branch-free, exact +-1 tails.
    float e = __builtin_amdgcn_exp2f(x * 2.8853900817779268f);
    return __builtin_fmaf(-2.0f, __builtin_amdgcn_rcpf(e + 1.0f), 1.0f);
}

// embW[v][i] = sum_j emb[v][j] * W_ih[i][j]  (fp32-exact input-projection table)
__global__ void rnn_prep_embw(const float* __restrict__ emb,
                              const float* __restrict__ W_ih,
                              float* __restrict__ embW) {
    const int v = blockIdx.x;
    const int i = threadIdx.x;
    __shared__ __align__(16) float e[HIDDEN];
    e[i] = emb[v * HIDDEN + i];
    __syncthreads();
    const float4* wrow = (const float4*)(W_ih + i * HIDDEN);
    const float4* e4 = (const float4*)e;
    float a0 = 0.f, a1 = 0.f, a2 = 0.f, a3 = 0.f;
#pragma unroll
    for (int j = 0; j < HIDDEN / 4; ++j) {
        float4 w = wrow[j];
        float4 h = e4[j];
        a0 += w.x * h.x; a1 += w.y * h.y; a2 += w.z * h.z; a3 += w.w * h.w;
    }
    embW[v * HIDDEN + i] = (a0 + a1) + (a2 + a3);
}

// One block per 16 batch rows; 4 waves, wave w owns output cols [32w,32w+32).
// fp16 single-product recurrence: W_hh fp16 B-fragments in VGPRs, h fp16 in LDS
// (double-buffered). Per step: 4 ds_read_b128 -> 8 MFMA (4 indep 2-chains) ->
// tanh -> 8 ds_write_b16 -> barrier. embW seed is fp32, prefetched 1 step ahead.
__global__ void __launch_bounds__(256)
rnn_mfma(const int* __restrict__ x, const int* __restrict__ lengths,
         const float* __restrict__ embW, const float* __restrict__ W_hh,
         const float* __restrict__ W_fc, const float* __restrict__ b_fc,
         float* __restrict__ out) {
    const int tid = threadIdx.x;
    const int wave = tid >> 6;
    const int lane = tid & 63;
    const int q = lane >> 4;     // 0..3  (k-group for A/B frags; row-group for C)
    const int r16 = lane & 15;   // 0..15 (A row / B-N col / C col)
    const int c0 = wave * 32;
    const int b0 = blockIdx.x * MTILE;

    __shared__ __align__(16) _Float16 Ah[2][MTILE][ASTRIDE];
    __shared__ int xs[MTILE][XSTRIDE];
    __shared__ __align__(16) float hfin[MTILE][HIDDEN];
    __shared__ int lenbuf[MTILE];

    // Stage tokens (coalesced) and lengths.
    for (int idx = tid; idx < MTILE * SEQ; idx += 256) {
        int r = idx >> 8, t = idx & (SEQ - 1);
        xs[r][t] = x[(b0 + r) * SEQ + t];
    }
    if (tid < MTILE) lenbuf[tid] = lengths[b0 + tid];

    // h_0 = 0 in both buffers.
    for (int idx = tid; idx < 2 * MTILE * ASTRIDE; idx += 256)
        ((_Float16*)Ah)[idx] = (_Float16)0.0f;

    // B-fragments: lane holds B[k=kc*32+q*8+j][n=r16] = W_hh[col][k] (z = h @ W_hh^T).
    f16x8 B[2][4];
#pragma unroll
    for (int n = 0; n < 2; ++n) {
        const float* wrow = W_hh + (c0 + 16 * n + r16) * HIDDEN + q * 8;
#pragma unroll
        for (int kc = 0; kc < 4; ++kc) {
            const float* p = wrow + kc * 32;
#pragma unroll
            for (int j = 0; j < 8; ++j) B[n][kc][j] = (_Float16)p[j];
        }
    }

    __syncthreads();

    int len4[4];
#pragma unroll
    for (int v = 0; v < 4; ++v) len4[v] = lenbuf[4 * q + v];
    int lenmax = 0;
    for (int r = 0; r < MTILE; ++r) lenmax = max(lenmax, lenbuf[r]);

    // fp32 embW seed for t=0 (C layout: lane owns rows 4q+v, cols c0+r16 / +16).
    f32x4 pre0, pre1;
#pragma unroll
    for (int v = 0; v < 4; ++v) {
        int tok = xs[4 * q + v][0];
        pre0[v] = embW[tok * HIDDEN + c0 + r16];
        pre1[v] = embW[tok * HIDDEN + c0 + 16 + r16];
    }

    int cur = 0;
    f32x4 hout0 = {0.f, 0.f, 0.f, 0.f}, hout1 = {0.f, 0.f, 0.f, 0.f};

    for (int t = 0; t < lenmax; ++t) {
        // A-fragments for this step (issue all reads up front).
        f16x8 A0 = *(const f16x8*)&Ah[cur][r16][0 * 32 + q * 8];
        f16x8 A1 = *(const f16x8*)&Ah[cur][r16][1 * 32 + q * 8];
        f16x8 A2 = *(const f16x8*)&Ah[cur][r16][2 * 32 + q * 8];
        f16x8 A3 = *(const f16x8*)&Ah[cur][r16][3 * 32 + q * 8];

        // Prefetch next step's embW seed (independent; hides L1/L2 latency).
        const int tn = (t + 1 < lenmax) ? t + 1 : t;
        f32x4 pn0, pn1;
#pragma unroll
        for (int v = 0; v < 4; ++v) {
            int tok = xs[4 * q + v][tn];
            pn0[v] = embW[tok * HIDDEN + c0 + r16];
            pn1[v] = embW[tok * HIDDEN + c0 + 16 + r16];
        }

        // Split-K: 4 independent 2-deep MFMA chains.
        f32x4 a0 = pre0, a1 = pre1;
        f32x4 b0c = {0.f, 0.f, 0.f, 0.f}, b1c = {0.f, 0.f, 0.f, 0.f};
        a0  = __builtin_amdgcn_mfma_f32_16x16x32_f16(A0, B[0][0], a0, 0, 0, 0);
        a1  = __builtin_amdgcn_mfma_f32_16x16x32_f16(A0, B[1][0], a1, 0, 0, 0);
        b0c = __builtin_amdgcn_mfma_f32_16x16x32_f16(A2, B[0][2], b0c, 0, 0, 0);
        b1c = __builtin_amdgcn_mfma_f32_16x16x32_f16(A2, B[1][2], b1c, 0, 0, 0);
        a0  = __builtin_amdgcn_mfma_f32_16x16x32_f16(A1, B[0][1], a0, 0, 0, 0);
        a1  = __builtin_amdgcn_mfma_f32_16x16x32_f16(A1, B[1][1], a1, 0, 0, 0);
        b0c = __builtin_amdgcn_mfma_f32_16x16x32_f16(A3, B[0][3], b0c, 0, 0, 0);
        b1c = __builtin_amdgcn_mfma_f32_16x16x32_f16(A3, B[1][3], b1c, 0, 0, 0);
        f32x4 z0 = a0 + b0c;
        f32x4 z1 = a1 + b1c;

        const int nxt = cur ^ 1;
#pragma unroll
        for (int v = 0; v < 4; ++v) {
            float h0 = fast_tanh(z0[v]);
            float h1 = fast_tanh(z1[v]);
            if (t + 1 == len4[v]) { hout0[v] = h0; hout1[v] = h1; }
            int rr = 4 * q + v;
            Ah[nxt][rr][c0 + r16] = (_Float16)h0;
            Ah[nxt][rr][c0 + 16 + r16] = (_Float16)h1;
        }
        __syncthreads();
        cur = nxt;
        pre0 = pn0; pre1 = pn1;
    }

    // Gather captured final h (fp32) and run the tiny FC epilogue.
#pragma unroll
    for (int v = 0; v < 4; ++v) {
        hfin[4 * q + v][c0 + r16] = hout0[v];
        hfin[4 * q + v][c0 + 16 + r16] = hout1[v];
    }
    __syncthreads();

    const int r = tid >> 4;       // 0..15
    const int vbase = tid & 15;   // 0..15
    const float4* hv = (const float4*)hfin[r];
    for (int vo = vbase; vo < VOCAB; vo += 16) {
        const float4* wf = (const float4*)(W_fc + vo * HIDDEN);
        float a0 = 0.f, a1 = 0.f, a2 = 0.f, a3 = 0.f;
#pragma unroll
        for (int j = 0; j < HIDDEN / 4; ++j) {
            float4 a = hv[j];
            float4 w = wf[j];
            a0 += a.x * w.x; a1 += a.y * w.y; a2 += a.z * w.z; a3 += a.w * w.w;
        }
        out[(b0 + r) * VOCAB + vo] = (a0 + a1) + (a2 + a3) + b_fc[vo];
    }
}

extern "C" void kernel_launch(void* const* d_in, const int* in_sizes, int n_in,
                              void* d_out, int out_size, void* d_ws, size_t ws_size,
                              hipStream_t stream) {
    const int* x = (const int*)d_in[0];          // [B, T] int32
    const int* lengths = (const int*)d_in[1];    // [B] int32
    const float* emb = (const float*)d_in[2];    // [V, H]
    const float* W_ih = (const float*)d_in[3];   // [H, H]
    const float* W_hh = (const float*)d_in[4];   // [H, H]
    const float* W_fc = (const float*)d_in[5];   // [V, H]
    const float* b_fc = (const float*)d_in[6];   // [V]
    float* out = (float*)d_out;                  // [B, V]

    float* embW = (float*)d_ws;                  // VOCAB*HIDDEN floats (30 KB)

    rnn_prep_embw<<<VOCAB, HIDDEN, 0, stream>>>(emb, W_ih, embW);
    rnn_mfma<<<BATCH / MTILE, 256, 0, stream>>>(x, lengths, embW, W_hh, W_fc, b_fc, out);
}

// Round 4
// 193.549 us; speedup vs baseline: 1.6403x; 1.0882x over previous
//
#include <hip/hip_runtime.h>
#include <hip/hip_bf16.h>

#define BATCH 1024
#define SEQ 256
#define HIDDEN 128
#define VOCAB 60
#define MTILE 16
#define ASTRIDE 136        // f16 per h row: 128 + 8 pad (68 dwords; 8-lane groups cover all 32 banks on b128)
#define XSTRIDE (SEQ + 1)  // pad token rows off bank alignment

typedef _Float16 f16x8 __attribute__((ext_vector_type(8)));
typedef _Float16 f16x4 __attribute__((ext_vector_type(4)));
typedef float f32x4 __attribute__((ext_vector_type(4)));

__device__ __forceinline__ float fast_tanh(float x) {
    // tanh(x) = 1 - 2/(exp(2x)+1); exp(2x)=exp2(x*2*log2e). Branch-free, exact +-1 tails.
    float e = __builtin_amdgcn_exp2f(x * 2.8853900817779268f);
    return __builtin_fmaf(-2.0f, __builtin_amdgcn_rcpf(e + 1.0f), 1.0f);
}

// embW[v][i] = sum_j emb[v][j] * W_ih[i][j]  (fp32-exact input-projection table)
__global__ void rnn_prep_embw(const float* __restrict__ emb,
                              const float* __restrict__ W_ih,
                              float* __restrict__ embW) {
    const int v = blockIdx.x;
    const int i = threadIdx.x;
    __shared__ __align__(16) float e[HIDDEN];
    e[i] = emb[v * HIDDEN + i];
    __syncthreads();
    const float4* wrow = (const float4*)(W_ih + i * HIDDEN);
    const float4* e4 = (const float4*)e;
    float a0 = 0.f, a1 = 0.f, a2 = 0.f, a3 = 0.f;
#pragma unroll
    for (int j = 0; j < HIDDEN / 4; ++j) {
        float4 w = wrow[j];
        float4 h = e4[j];
        a0 += w.x * h.x; a1 += w.y * h.y; a2 += w.z * h.z; a3 += w.w * h.w;
    }
    embW[v * HIDDEN + i] = (a0 + a1) + (a2 + a3);
}

// Transposed recurrence: z^T = W_hh * h^T.
// A-operand = W_hh rows (static f16 frags in VGPRs), B-operand = h^T (frag layout
// identical to row-major h reads: ds_read_b128 from Ah). C layout: lane owns
// batch row r16 and z-cols {c0+16nt+4q+v}. Per step per lane: 1 tok ds_read_b32
// (broadcast), 2 float4 embW loads (prefetched), 4 ds_read_b128, 8 MFMA
// (4 indep 2-chains), 8 tanh, 2 ds_write_b64, 1 barrier.
__global__ void __launch_bounds__(256)
rnn_mfma(const int* __restrict__ x, const int* __restrict__ lengths,
         const float* __restrict__ embW, const float* __restrict__ W_hh,
         const float* __restrict__ W_fc, const float* __restrict__ b_fc,
         float* __restrict__ out) {
    const int tid = threadIdx.x;
    const int wave = tid >> 6;
    const int lane = tid & 63;
    const int q = lane >> 4;     // 0..3
    const int r16 = lane & 15;   // 0..15 : this lane's batch row
    const int c0 = wave * 32;    // wave's z-col base (owns cols [c0, c0+32))
    const int b0 = blockIdx.x * MTILE;

    __shared__ __align__(16) _Float16 Ah[2][MTILE][ASTRIDE];
    __shared__ int xs[MTILE][XSTRIDE];
    __shared__ __align__(16) float hfin[MTILE][HIDDEN];
    __shared__ int lenbuf[MTILE];

    // Stage tokens (coalesced) and lengths.
    for (int idx = tid; idx < MTILE * SEQ; idx += 256) {
        int r = idx >> 8, t = idx & (SEQ - 1);
        xs[r][t] = x[(b0 + r) * SEQ + t];
    }
    if (tid < MTILE) lenbuf[tid] = lengths[b0 + tid];

    // h_0 = 0 in both buffers.
    for (int idx = tid; idx < 2 * MTILE * ASTRIDE; idx += 256)
        ((_Float16*)Ah)[idx] = (_Float16)0.0f;

    // Static A-frags of W_hh: lane holds A[m=r16][k=q*8+j] per (nt, kc) tile,
    // m_global = c0 + 16*nt + r16, k = kc*32 + q*8 + j.
    f16x8 Wf[2][4];
#pragma unroll
    for (int nt = 0; nt < 2; ++nt) {
        const float* wrow = W_hh + (c0 + 16 * nt + r16) * HIDDEN + q * 8;
#pragma unroll
        for (int kc = 0; kc < 4; ++kc) {
            const float* p = wrow + kc * 32;
#pragma unroll
            for (int j = 0; j < 8; ++j) Wf[nt][kc][j] = (_Float16)p[j];
        }
    }

    __syncthreads();

    const int mylen = lenbuf[r16];
    int lenmax = 0;
    for (int r = 0; r < MTILE; ++r) lenmax = max(lenmax, lenbuf[r]);

    // embW seed for t=0 (C layout: cols c0+16nt+4q+v for batch row r16).
    {
    }
    int tok0 = xs[r16][0];
    const float* eb0 = embW + tok0 * HIDDEN + c0 + 4 * q;
    f32x4 pre0 = *(const f32x4*)eb0;
    f32x4 pre1 = *(const f32x4*)(eb0 + 16);
    int tokn = xs[r16][1 < lenmax ? 1 : 0];  // token for t=1 (row always has SEQ entries)

    int cur = 0;
    f32x4 hout0 = {0.f, 0.f, 0.f, 0.f}, hout1 = {0.f, 0.f, 0.f, 0.f};

    for (int t = 0; t < lenmax; ++t) {
        // B-frags (h^T) for this step: identical addresses across all 4 waves.
        const _Float16* arow = &Ah[cur][r16][q * 8];
        f16x8 H0 = *(const f16x8*)(arow + 0);
        f16x8 H1 = *(const f16x8*)(arow + 32);
        f16x8 H2 = *(const f16x8*)(arow + 64);
        f16x8 H3 = *(const f16x8*)(arow + 96);

        // Prefetch embW seed for t+1 (tokn loaded last step), token for t+2.
        const float* eb = embW + tokn * HIDDEN + c0 + 4 * q;
        f32x4 pn0 = *(const f32x4*)eb;
        f32x4 pn1 = *(const f32x4*)(eb + 16);
        const int t2 = (t + 2 < lenmax) ? t + 2 : lenmax - 1;
        tokn = xs[r16][t2];

        // 4 independent 2-deep MFMA chains (split-K).
        f32x4 a0 = pre0, a1 = pre1;
        f32x4 d0 = {0.f, 0.f, 0.f, 0.f}, d1 = {0.f, 0.f, 0.f, 0.f};
        a0 = __builtin_amdgcn_mfma_f32_16x16x32_f16(Wf[0][0], H0, a0, 0, 0, 0);
        a1 = __builtin_amdgcn_mfma_f32_16x16x32_f16(Wf[1][0], H0, a1, 0, 0, 0);
        d0 = __builtin_amdgcn_mfma_f32_16x16x32_f16(Wf[0][2], H2, d0, 0, 0, 0);
        d1 = __builtin_amdgcn_mfma_f32_16x16x32_f16(Wf[1][2], H2, d1, 0, 0, 0);
        a0 = __builtin_amdgcn_mfma_f32_16x16x32_f16(Wf[0][1], H1, a0, 0, 0, 0);
        a1 = __builtin_amdgcn_mfma_f32_16x16x32_f16(Wf[1][1], H1, a1, 0, 0, 0);
        d0 = __builtin_amdgcn_mfma_f32_16x16x32_f16(Wf[0][3], H3, d0, 0, 0, 0);
        d1 = __builtin_amdgcn_mfma_f32_16x16x32_f16(Wf[1][3], H3, d1, 0, 0, 0);
        f32x4 z0 = a0 + d0;
        f32x4 z1 = a1 + d1;

        f32x4 th0, th1;
#pragma unroll
        for (int v = 0; v < 4; ++v) {
            th0[v] = fast_tanh(z0[v]);
            th1[v] = fast_tanh(z1[v]);
        }
        if (t + 1 == mylen) { hout0 = th0; hout1 = th1; }

        // Pack 4 f16 per tile and write back (8B aligned, 2 writes/lane).
        const int nxt = cur ^ 1;
        f16x4 w0, w1;
#pragma unroll
        for (int v = 0; v < 4; ++v) {
            w0[v] = (_Float16)th0[v];
            w1[v] = (_Float16)th1[v];
        }
        *(f16x4*)&Ah[nxt][r16][c0 + 4 * q] = w0;
        *(f16x4*)&Ah[nxt][r16][c0 + 16 + 4 * q] = w1;
        __syncthreads();
        cur = nxt;
        pre0 = pn0; pre1 = pn1;
    }

    // Final h (fp32) -> LDS, then tiny FC epilogue.
#pragma unroll
    for (int v = 0; v < 4; ++v) {
        hfin[r16][c0 + 4 * q + v] = hout0[v];
        hfin[r16][c0 + 16 + 4 * q + v] = hout1[v];
    }
    __syncthreads();

    const int r = tid >> 4;       // 0..15
    const int vbase = tid & 15;   // 0..15
    const float4* hv = (const float4*)hfin[r];
    for (int vo = vbase; vo < VOCAB; vo += 16) {
        const float4* wf = (const float4*)(W_fc + vo * HIDDEN);
        float a0 = 0.f, a1 = 0.f, a2 = 0.f, a3 = 0.f;
#pragma unroll
        for (int j = 0; j < HIDDEN / 4; ++j) {
            float4 a = hv[j];
            float4 w = wf[j];
            a0 += a.x * w.x; a1 += a.y * w.y; a2 += a.z * w.z; a3 += a.w * w.w;
        }
        out[(b0 + r) * VOCAB + vo] = (a0 + a1) + (a2 + a3) + b_fc[vo];
    }
}

extern "C" void kernel_launch(void* const* d_in, const int* in_sizes, int n_in,
                              void* d_out, int out_size, void* d_ws, size_t ws_size,
                              hipStream_t stream) {
    const int* x = (const int*)d_in[0];          // [B, T] int32
    const int* lengths = (const int*)d_in[1];    // [B] int32
    const float* emb = (const float*)d_in[2];    // [V, H]
    const float* W_ih = (const float*)d_in[3];   // [H, H]
    const float* W_hh = (const float*)d_in[4];   // [H, H]
    const float* W_fc = (const float*)d_in[5];   // [V, H]
    const float* b_fc = (const float*)d_in[6];   // [V]
    float* out = (float*)d_out;                  // [B, V]

    float* embW = (float*)d_ws;                  // VOCAB*HIDDEN floats (30 KB)

    rnn_prep_embw<<<VOCAB, HIDDEN, 0, stream>>>(emb, W_ih, embW);
    rnn_mfma<<<BATCH / MTILE, 256, 0, stream>>>(x, lengths, embW, W_hh, W_fc, b_fc, out);
}